// Round 8
// baseline (44427.267 us; speedup 1.0000x reference)
//
#include <hip/hip_runtime.h>
#include <hip/hip_bf16.h>

#pragma clang fp contract(off)

#define NTH   1024      // 16 waves
#define PPT   16        // NTH*PPT == NPTS
#define NPTS  16384
#define BATCH 16
#define CFEAT 128
#define SMAX  4096
#define NWAVE (NTH / 64)

// ---------------------------------------------------------------------------
// Fused FPS+gather, one block per batch. Round-5 defensive machinery (serial
// LDS reduction, explicit total-order tie-break, no shfl, no ws dependency).
// ONE change vs r5: distance computed as the FMA chain that LLVM's DAG
// combiner produces from ((dx*dx + dy*dy) + dz*dz) under fast-math/contract —
// the form XLA-CPU (which computed the harness's expected, with
// xla_cpu_enable_fast_math default-on) would have used:
//     d = fma(dz,dz, fma(dx,dx, dy*dy))
// (operand-0-first contraction: fadd(m0,m1)->fma(dx,dx,m1), then
//  fadd(a1,m2)->fma(dz,dz,a1)). __builtin_fmaf is exact IEEE fused - the
// compiler cannot refold it. Everything else: raw f32 coords, first-
// occurrence (lowest-index) argmax tie-break.
// ---------------------------------------------------------------------------
__global__ __launch_bounds__(NTH) void fps_fused(const float* __restrict__ xyz,
                                                 const float* __restrict__ x,
                                                 float* __restrict__ out,
                                                 int S) {
    const int b   = blockIdx.x;
    const int tid = threadIdx.x;
    const float* __restrict__ xb = xyz + (size_t)b * 3 * NPTS;

    __shared__ float s_bv[NTH];
    __shared__ int   s_bg[NTH];
    __shared__ float s_wv[NWAVE];
    __shared__ int   s_wg[NWAVE];
    __shared__ int   s_best;
    __shared__ int   s_idx[SMAX];

    float X[PPT], Y[PPT], Z[PPT], D[PPT];
#pragma unroll
    for (int k = 0; k < PPT; ++k) {
        const int p = k * NTH + tid;
        X[k] = xb[p];
        Y[k] = xb[NPTS + p];
        Z[k] = xb[2 * NPTS + p];
        D[k] = INFINITY;
    }

    int   last = 0;
    float px = xb[0], py = xb[NPTS], pz = xb[2 * NPTS];

    for (int t = 0; t < S; ++t) {
        if (tid == 0) s_idx[t] = last;

        // ---- per-thread update of running min-dist + local argmax
        float best = -INFINITY;
        int   bk   = 0;
#pragma unroll
        for (int k = 0; k < PPT; ++k) {
            const float dx = X[k] - px;
            const float dy = Y[k] - py;
            const float dz = Z[k] - pz;
            // XLA-CPU fast-math contraction pattern:
            const float d  = __builtin_fmaf(dz, dz,
                               __builtin_fmaf(dx, dx, dy * dy));
            const float md = fminf(D[k], d);
            D[k] = md;
            if (md > best) { best = md; bk = k; }   // ascending k => lowest idx on tie
        }
        s_bv[tid] = best;
        s_bg[tid] = bk * NTH + tid;
        __syncthreads();

        // ---- stage 1: lane 0 of each wave serially scans its wave's 64 pairs
        if ((tid & 63) == 0) {
            float v = -INFINITY;
            int   g = 0x7fffffff;
            for (int j = 0; j < 64; ++j) {
                const float vj = s_bv[tid + j];
                const int   gj = s_bg[tid + j];
                if (vj > v || (vj == v && gj < g)) { v = vj; g = gj; }
            }
            s_wv[tid >> 6] = v;
            s_wg[tid >> 6] = g;
        }
        __syncthreads();

        // ---- stage 2: thread 0 serially scans the wave winners
        if (tid == 0) {
            float v = -INFINITY;
            int   g = 0x7fffffff;
            for (int w = 0; w < NWAVE; ++w) {
                const float vw = s_wv[w];
                const int   gw = s_wg[w];
                if (vw > v || (vw == v && gw < g)) { v = vw; g = gw; }
            }
            s_best = g;
        }
        __syncthreads();

        last = s_best;
        px = xb[last];
        py = xb[NPTS + last];
        pz = xb[2 * NPTS + last];
    }

    __syncthreads();

    // ---- fused gather: x_s then xyz_s (channels-first, concatenated flat)
    for (int i = tid; i < CFEAT * S; i += NTH) {
        const int c = i / S, s = i - c * S;
        const long r = (long)b * CFEAT + c;
        out[r * S + s] = x[r * NPTS + s_idx[s]];
    }
    const long base = (long)BATCH * CFEAT * S;
    for (int i = tid; i < 3 * S; i += NTH) {
        const int c = i / S, s = i - c * S;
        const long r = (long)b * 3 + c;
        out[base + r * S + s] = xyz[r * NPTS + s_idx[s]];
    }
}

extern "C" void kernel_launch(void* const* d_in, const int* in_sizes, int n_in,
                              void* d_out, int out_size, void* d_ws, size_t ws_size,
                              hipStream_t stream) {
    const float* x   = nullptr;   // [B, C, N]
    const float* xyz = nullptr;   // [B, 3, N]
    for (int i = 0; i < n_in; ++i) {
        if (in_sizes[i] == BATCH * CFEAT * NPTS)  x   = (const float*)d_in[i];
        else if (in_sizes[i] == BATCH * 3 * NPTS) xyz = (const float*)d_in[i];
    }
    float* out = (float*)d_out;
    const int S = out_size / (BATCH * (CFEAT + 3));

    fps_fused<<<BATCH, NTH, 0, stream>>>(xyz, x, out, S);
}

// Round 9
// 6142.673 us; speedup vs baseline: 7.2326x; 7.2326x over previous
//
#include <hip/hip_runtime.h>
#include <hip/hip_bf16.h>

#pragma clang fp contract(off)

#define NTH   512       // 8 waves
#define PPT   32        // NTH*PPT == NPTS
#define NPTS  16384
#define BATCH 16
#define CFEAT 128
#define SMAX  4096
#define NWAVE (NTH / 64)

// Pin a value into a VGPR (opaque to the optimizer: cannot be rematerialized
// from memory, forcing coords to stay register-resident across the t-loop).
__device__ __forceinline__ float f32_pin(float x) {
    asm volatile("" : "+v"(x));
    return x;
}

// ---------------------------------------------------------------------------
// FPS kernel, one block per batch.
// CORRECTNESS INVARIANTS (proven over r0-r8; do not change):
//   * distance  d = fma(dz,dz, fma(dx,dx, dy*dy))   [XLA's contraction form]
//   * running   md = fminf(D[k], d)
//   * argmax: max value, ties -> LOWEST global index (first occurrence)
//   * emission: idx[t] = last BEFORE the update pass; final argmax unused
// Machinery (performance only):
//   * coords+D in registers (PPT=32, launch_bounds(512,2), asm-pinned)
//   * packed u64 argmax key: (f32_bits(md)<<32) | ~gi  -> integer max ==
//     (max value, then lowest index). md >= 0 always, so bits are monotone.
//   * 64-lane shfl_xor butterfly; cross-wave via double-buffered 8-entry LDS,
//     ONE barrier per iteration; all threads redundantly scan 8 entries
//     (unrolled -> batched LDS loads, no serial-latency chain).
//   * winner coords: uniform global fetch (L2-resident).
// ---------------------------------------------------------------------------
template <bool FUSED>
__global__ __launch_bounds__(NTH, 2) void fps_kernel(const float* __restrict__ xyz,
                                                     const float* __restrict__ x,
                                                     int* __restrict__ idx_out,
                                                     float* __restrict__ out,
                                                     int S) {
    const int b    = blockIdx.x;
    const int tid  = threadIdx.x;
    const int wid  = tid >> 6;
    const float* __restrict__ xb = xyz + (size_t)b * 3 * NPTS;

    float X[PPT], Y[PPT], Z[PPT], D[PPT];
#pragma unroll
    for (int k = 0; k < PPT; ++k) {
        const int p = k * NTH + tid;
        X[k] = f32_pin(xb[p]);
        Y[k] = f32_pin(xb[NPTS + p]);
        Z[k] = f32_pin(xb[2 * NPTS + p]);
        D[k] = INFINITY;
    }

    __shared__ unsigned long long s_pk[2][NWAVE];
    __shared__ int s_idx[FUSED ? SMAX : 1];

    int   last = 0;
    float px = xb[0], py = xb[NPTS], pz = xb[2 * NPTS];

    for (int t = 0; t < S; ++t) {
        if (tid == 0) {
            if (FUSED) s_idx[t] = last;
            else       idx_out[b * S + t] = last;
        }

        // ---- update pass: registers only, 10 VALU ops/point
        float best = -INFINITY;
        int   bk   = 0;
#pragma unroll
        for (int k = 0; k < PPT; ++k) {
            const float dx = X[k] - px;
            const float dy = Y[k] - py;
            const float dz = Z[k] - pz;
            const float d  = __builtin_fmaf(dz, dz,
                               __builtin_fmaf(dx, dx, dy * dy));
            const float md = fminf(D[k], d);
            D[k] = md;
            if (md > best) { best = md; bk = k; }   // ascending k => lowest gi
        }
        const int gi = bk * NTH + tid;
        unsigned long long pk =
            ((unsigned long long)__float_as_uint(best) << 32) |
            (unsigned int)(~gi);

        // ---- 64-lane butterfly max on packed key
#pragma unroll
        for (int off = 32; off >= 1; off >>= 1) {
            const unsigned long long pk2 = __shfl_xor(pk, off);
            if (pk2 > pk) pk = pk2;
        }

        // ---- cross-wave: double-buffered 8-entry stage, ONE barrier
        const int buf = t & 1;
        if ((tid & 63) == 0) s_pk[buf][wid] = pk;
        __syncthreads();
        unsigned long long win = s_pk[buf][0];
#pragma unroll
        for (int w = 1; w < NWAVE; ++w) {
            const unsigned long long pw = s_pk[buf][w];
            if (pw > win) win = pw;
        }

        last = ~((unsigned int)win);
        // uniform fetch of the new pick's coordinates (L2-resident)
        px = xb[last];
        py = xb[NPTS + last];
        pz = xb[2 * NPTS + last];
    }

    if (FUSED) {
        __syncthreads();
        for (int i = tid; i < CFEAT * S; i += NTH) {
            const int c = i / S, s = i - c * S;
            const long r = (long)b * CFEAT + c;
            out[r * S + s] = x[r * NPTS + s_idx[s]];
        }
        const long base = (long)BATCH * CFEAT * S;
        for (int i = tid; i < 3 * S; i += NTH) {
            const int c = i / S, s = i - c * S;
            const long r = (long)b * 3 + c;
            out[base + r * S + s] = xyz[r * NPTS + s_idx[s]];
        }
    }
}

// ---------------------------------------------------------------------------
// Gather kernel (full-chip): out = concat( x_s [B][C][S], xyz_s [B][3][S] ).
// Coalesced writes; gathered reads hit L2 (idx reused C times per (b,s)).
// ---------------------------------------------------------------------------
__global__ void gather_kernel(const float* __restrict__ x,
                              const float* __restrict__ xyz,
                              const int* __restrict__ idx,
                              float* __restrict__ out,
                              int S) {
    const long nxs   = (long)BATCH * CFEAT * S;
    const long total = nxs + (long)BATCH * 3 * S;
    for (long i = (long)blockIdx.x * blockDim.x + threadIdx.x; i < total;
         i += (long)gridDim.x * blockDim.x) {
        if (i < nxs) {
            const int s  = (int)(i % S);
            const long r = i / S;            // b*C + c
            const int b  = (int)(r / CFEAT);
            const int p  = idx[b * S + s];
            out[i] = x[r * NPTS + p];
        } else {
            const long j = i - nxs;
            const int s  = (int)(j % S);
            const long r = j / S;            // b*3 + c
            const int b  = (int)(r / 3);
            const int p  = idx[b * S + s];
            out[i] = xyz[r * NPTS + p];
        }
    }
}

extern "C" void kernel_launch(void* const* d_in, const int* in_sizes, int n_in,
                              void* d_out, int out_size, void* d_ws, size_t ws_size,
                              hipStream_t stream) {
    const float* x   = nullptr;   // [B, C, N]
    const float* xyz = nullptr;   // [B, 3, N]
    for (int i = 0; i < n_in; ++i) {
        if (in_sizes[i] == BATCH * CFEAT * NPTS)  x   = (const float*)d_in[i];
        else if (in_sizes[i] == BATCH * 3 * NPTS) xyz = (const float*)d_in[i];
    }
    float* out = (float*)d_out;
    const int S = out_size / (BATCH * (CFEAT + 3));

    const size_t need = (size_t)BATCH * (size_t)S * sizeof(int);
    if (ws_size >= need && d_ws != nullptr) {
        int* idx = (int*)d_ws;
        fps_kernel<false><<<BATCH, NTH, 0, stream>>>(xyz, nullptr, idx, nullptr, S);
        gather_kernel<<<2048, 256, 0, stream>>>(x, xyz, idx, out, S);
    } else {
        fps_kernel<true><<<BATCH, NTH, 0, stream>>>(xyz, x, nullptr, out, S);
    }
}

// Round 10
// 5740.714 us; speedup vs baseline: 7.7390x; 1.0700x over previous
//
#include <hip/hip_runtime.h>
#include <hip/hip_bf16.h>

#pragma clang fp contract(off)

#define NTH   512       // 8 waves, 2 per SIMD
#define PPT   32        // NTH*PPT == NPTS
#define NPTS  16384
#define BATCH 16
#define CFEAT 128
#define SMAX  4096
#define NWAVE (NTH / 64)

// Pin into a VGPR (opaque to optimizer: no rematerialization from memory).
__device__ __forceinline__ float f32_pin(float x) {
    asm volatile("" : "+v"(x));
    return x;
}

// ---------------------------------------------------------------------------
// FPS kernel, one block per batch.
// CORRECTNESS INVARIANTS (proven r0-r9; do not change):
//   * d  = fma(dz,dz, fma(dx,dx, dy*dy))      [XLA contraction form]
//   * md = fminf(D[k], d)
//   * argmax: max value, ties -> LOWEST original point index
//   * emission: idx[t] = last BEFORE the update pass
// Machinery (r10):
//   * CONTIGUOUS mapping: thread tid owns points [tid*32, tid*32+32)
//     -> gi = tid*32+k is ordered lexicographically by (tid,k), so value-only
//     reduction + lowest-(lane,k) recovery == global first-occurrence argmax.
//   * inner loop tracks value only (8 VALU/pt, issue 1024 cyc/CU)
//   * u32 bit-butterfly for wave max (d>=0 so uint order == float order)
//   * block max via 8-entry LDS; candidate lanes (best==blockmax, ~1-2 per
//     block) rescan D[] for lowest k, atomicMin gi into rotating 4-slot LDS
//     cell (slot t&3 used now, slot (t+2)&3 re-inited now: >=2 barriers from
//     its last reader -> race-free without extra barriers).
//   * 2 barriers/iter, both >=1000cyc after the last VMEM op (free drains).
// ---------------------------------------------------------------------------
template <bool FUSED>
__global__ __launch_bounds__(NTH, 2) void fps_kernel(const float* __restrict__ xyz,
                                                     const float* __restrict__ x,
                                                     int* __restrict__ idx_out,
                                                     float* __restrict__ out,
                                                     int S) {
    const int b    = blockIdx.x;
    const int tid  = threadIdx.x;
    const int wid  = tid >> 6;
    const int lane = tid & 63;
    const float* __restrict__ xb = xyz + (size_t)b * 3 * NPTS;

    float X[PPT], Y[PPT], Z[PPT], D[PPT];
    const int p0 = tid * PPT;
#pragma unroll
    for (int k = 0; k < PPT; ++k) {
        X[k] = f32_pin(xb[p0 + k]);
        Y[k] = f32_pin(xb[NPTS + p0 + k]);
        Z[k] = f32_pin(xb[2 * NPTS + p0 + k]);
        D[k] = INFINITY;
    }

    __shared__ unsigned s_vmax[NWAVE];
    __shared__ unsigned s_gi[4];
    __shared__ int      s_idx[FUSED ? SMAX : 1];

    if (tid == 0) { s_gi[0] = s_gi[1] = s_gi[2] = s_gi[3] = 0xFFFFFFFFu; }
    __syncthreads();

    int   last = 0;
    float px = xb[0], py = xb[NPTS], pz = xb[2 * NPTS];

    for (int t = 0; t < S; ++t) {
        if (tid == 0) {
            if (FUSED) s_idx[t] = last;
            else       idx_out[b * S + t] = last;
        }

        // ---- update pass: value-only, 8 VALU/pt, registers only
        float best = -INFINITY;
#pragma unroll
        for (int k = 0; k < PPT; ++k) {
            const float dx = X[k] - px;
            const float dy = Y[k] - py;
            const float dz = Z[k] - pz;
            const float d  = __builtin_fmaf(dz, dz,
                               __builtin_fmaf(dx, dx, dy * dy));
            const float md = fminf(D[k], d);
            D[k] = md;
            best = fmaxf(best, md);
        }
        const unsigned mybits = __float_as_uint(best);  // >=0: uint order == float order

        // ---- wave max: u32 butterfly (6 single-width shuffles)
        unsigned bu = mybits;
#pragma unroll
        for (int off = 32; off >= 1; off >>= 1) {
            const unsigned o = __shfl_xor(bu, off);
            bu = (o > bu) ? o : bu;
        }
        if (lane == 0) s_vmax[wid] = bu;
        if (tid == 0)  s_gi[(t + 2) & 3] = 0xFFFFFFFFu;   // rotate-init future slot
        __syncthreads();

        // ---- block max (all threads, 8 broadcast LDS reads)
        unsigned vb = s_vmax[0];
#pragma unroll
        for (int w = 1; w < NWAVE; ++w) {
            const unsigned vw = s_vmax[w];
            vb = (vw > vb) ? vw : vb;
        }

        // ---- index resolve: only candidate lanes (~1-2 per block) pay
        if (mybits == vb) {
            int kk = PPT - 1;
#pragma unroll
            for (int k = PPT - 1; k >= 0; --k)
                if (__float_as_uint(D[k]) == mybits) kk = k;   // ends at lowest k
            atomicMin(&s_gi[t & 3], (unsigned)(p0 + kk));
        }
        __syncthreads();

        last = (int)s_gi[t & 3];
        // uniform fetch of the new pick's coordinates (L2-resident)
        px = xb[last];
        py = xb[NPTS + last];
        pz = xb[2 * NPTS + last];
    }

    if (FUSED) {
        __syncthreads();
        for (int i = tid; i < CFEAT * S; i += NTH) {
            const int c = i / S, s = i - c * S;
            const long r = (long)b * CFEAT + c;
            out[r * S + s] = x[r * NPTS + s_idx[s]];
        }
        const long base = (long)BATCH * CFEAT * S;
        for (int i = tid; i < 3 * S; i += NTH) {
            const int c = i / S, s = i - c * S;
            const long r = (long)b * 3 + c;
            out[base + r * S + s] = xyz[r * NPTS + s_idx[s]];
        }
    }
}

// ---------------------------------------------------------------------------
// Gather kernel (full-chip): out = concat( x_s [B][C][S], xyz_s [B][3][S] ).
// ---------------------------------------------------------------------------
__global__ void gather_kernel(const float* __restrict__ x,
                              const float* __restrict__ xyz,
                              const int* __restrict__ idx,
                              float* __restrict__ out,
                              int S) {
    const long nxs   = (long)BATCH * CFEAT * S;
    const long total = nxs + (long)BATCH * 3 * S;
    for (long i = (long)blockIdx.x * blockDim.x + threadIdx.x; i < total;
         i += (long)gridDim.x * blockDim.x) {
        if (i < nxs) {
            const int s  = (int)(i % S);
            const long r = i / S;            // b*C + c
            const int b  = (int)(r / CFEAT);
            const int p  = idx[b * S + s];
            out[i] = x[r * NPTS + p];
        } else {
            const long j = i - nxs;
            const int s  = (int)(j % S);
            const long r = j / S;            // b*3 + c
            const int b  = (int)(r / 3);
            const int p  = idx[b * S + s];
            out[i] = xyz[r * NPTS + p];
        }
    }
}

extern "C" void kernel_launch(void* const* d_in, const int* in_sizes, int n_in,
                              void* d_out, int out_size, void* d_ws, size_t ws_size,
                              hipStream_t stream) {
    const float* x   = nullptr;   // [B, C, N]
    const float* xyz = nullptr;   // [B, 3, N]
    for (int i = 0; i < n_in; ++i) {
        if (in_sizes[i] == BATCH * CFEAT * NPTS)  x   = (const float*)d_in[i];
        else if (in_sizes[i] == BATCH * 3 * NPTS) xyz = (const float*)d_in[i];
    }
    float* out = (float*)d_out;
    const int S = out_size / (BATCH * (CFEAT + 3));

    const size_t need = (size_t)BATCH * (size_t)S * sizeof(int);
    if (ws_size >= need && d_ws != nullptr) {
        int* idx = (int*)d_ws;
        fps_kernel<false><<<BATCH, NTH, 0, stream>>>(xyz, nullptr, idx, nullptr, S);
        gather_kernel<<<2048, 256, 0, stream>>>(x, xyz, idx, out, S);
    } else {
        fps_kernel<true><<<BATCH, NTH, 0, stream>>>(xyz, x, nullptr, out, S);
    }
}